// Round 8
// baseline (147.985 us; speedup 1.0000x reference)
//
#include <hip/hip_runtime.h>
#include <math.h>

#define NQ   8192
#define MK   8192
#define KEEP 4096
#define NBLK 256

// ---- ws byte offsets ----
#define OFF_BAR    0          // 64 B: 4 (cnt,flag) pairs, memset to 0 pre-launch
#define OFF_KCNT   64         // 256 u32 per-block batch0 key counts
#define OFF_QCNT   1088       // 256 u32 per-block batch0 query counts
#define OFF_KPART  2112       // 8192 float4 partitioned keys {b,z,y,x}
#define OFF_QPART  133184     // 8192 float4 queries {z,y,x,idx_bits}
#define OFF_CMAX   264256     // 256 blk x 256 q f32 chunk max
#define OFF_PART   526400     // 256 blk x 256 q float4 chunk partials
#define OFF_K64    1574976    // 8192 u64 sort keys

// out layout (floats):
//   [0,16384) coords | [16384,98304) voxels | [98304,102400) kept_imp
//   [102400,110592) importance

typedef unsigned long long ull;

__device__ __forceinline__ void grid_barrier(unsigned* bar, int ph) {
    __syncthreads();
    if (threadIdx.x == 0) {
        __threadfence();
        unsigned prev = atomicAdd(bar + ph * 2, 1u);
        if (prev == NBLK - 1u) {
            atomicExch(bar + ph * 2 + 1, 1u);
        } else {
            while (atomicAdd(bar + ph * 2 + 1, 0u) == 0u)
                __builtin_amdgcn_s_sleep(2);
        }
        __threadfence();
    }
    __syncthreads();
}

__global__ __launch_bounds__(1024) void fused_kernel(
    const int4*   __restrict__ vcoords,   // N x 4 [b,z,y,x]
    const float4* __restrict__ kcoords,   // M x 4 [b,z,y,x]
    const float*  __restrict__ voxels,    // N x 5 x 4
    const float*  __restrict__ w1, const float* __restrict__ b1v,
    const float*  __restrict__ w2, const float* __restrict__ b2v,
    float* __restrict__ out,
    void*  __restrict__ wsv)
{
    __shared__ __align__(16) char smem[65792];   // sk / red1 / red2 / pf union
    __shared__ int shdr[4];                       // kOff, kc0t, qOff, qc0t
    __shared__ int scnt[16][32];
    __shared__ int rks[32];

    unsigned* bar  = (unsigned*)((char*)wsv + OFF_BAR);
    unsigned* kcnt = (unsigned*)((char*)wsv + OFF_KCNT);
    unsigned* qcnt = (unsigned*)((char*)wsv + OFF_QCNT);
    float4*   kpart = (float4*)((char*)wsv + OFF_KPART);
    float4*   qpart = (float4*)((char*)wsv + OFF_QPART);
    float*    cmaxg = (float*)((char*)wsv + OFF_CMAX);
    float4*   partg = (float4*)((char*)wsv + OFF_PART);
    ull*      K64   = (ull*)((char*)wsv + OFF_K64);

    const int b = blockIdx.x, t = threadIdx.x;
    const int w = t >> 6, lane = t & 63;

    // ========== P0: per-block batch0 counts (wave0: 32 keys, wave1: 32 queries)
    float4 myK = make_float4(0,0,0,0);
    int4   myQ = make_int4(0,0,0,0);
    ull blK = 0, blQ = 0;
    if (w == 0) {
        if (lane < 32) myK = kcoords[b * 32 + lane];
        blK = __ballot((lane < 32) && (myK.x == 0.0f));
        if (lane == 0) kcnt[b] = (unsigned)__popcll(blK);
    } else if (w == 1) {
        if (lane < 32) myQ = vcoords[b * 32 + lane];
        blQ = __ballot((lane < 32) && (myQ.x == 0));
        if (lane == 0) qcnt[b] = (unsigned)__popcll(blQ);
    }
    grid_barrier(bar, 0);

    // ========== P1: global prefix (per-block redundant) + stable scatter ====
    if (w < 2) {
        const unsigned* cnt = (w == 0) ? kcnt : qcnt;
        unsigned c0 = cnt[4*lane], c1 = cnt[4*lane+1],
                 c2 = cnt[4*lane+2], c3 = cnt[4*lane+3];
        unsigned s = c0 + c1 + c2 + c3;
        unsigned sc = s;
        #pragma unroll
        for (int off = 1; off < 64; off <<= 1) {
            unsigned v = __shfl_up(sc, off);
            if (lane >= off) sc += v;
        }
        unsigned tot  = __shfl(sc, 63);
        unsigned excl = sc - s;
        const int lb = b >> 2, rb = b & 3;
        unsigned p = (rb == 0) ? 0u : (rb == 1) ? c0 :
                     (rb == 2) ? (c0 + c1) : (c0 + c1 + c2);
        unsigned base = (unsigned)__shfl((int)excl, lb) + (unsigned)__shfl((int)p, lb);
        if (lane == 0) { shdr[w * 2] = (int)base; shdr[w * 2 + 1] = (int)tot; }
    }
    __syncthreads();
    const int kOff = shdr[0], kc0 = shdr[1];
    const int qOff = shdr[2], qc0 = shdr[3];

    if (w == 0 && lane < 32) {
        bool p0 = (myK.x == 0.0f);
        int bef = (int)__popcll(blK & ((1ull << lane) - 1));
        int gi = b * 32 + lane;
        int dst = p0 ? (kOff + bef) : (kc0 + gi - (kOff + bef));
        kpart[dst] = myK;
    } else if (w == 1 && lane < 32) {
        bool p0 = (myQ.x == 0);
        int bef = (int)__popcll(blQ & ((1ull << lane) - 1));
        int gi = b * 32 + lane;
        int dst = p0 ? (qOff + bef) : (qc0 + gi - (qOff + bef));
        qpart[dst] = make_float4((float)myQ.y, (float)myQ.z, (float)myQ.w,
                                 __int_as_float(gi));
    }
    grid_barrier(bar, 1);

    // ========== P2: attention — block = (q-group g of 256, key-chunk c of 8)
    {
        float4* sk   = (float4*)smem;
        float*  red1 = (float*)(smem + 16384);
        float*  red2 = (float*)(smem + 16384 + 16448);
        float4* pf   = (float4*)smem;

        const int g = b >> 3, c = b & 7;
        const int gs = g * 256;
        const bool uni1 = (gs >= qc0);
        const bool uni  = (gs + 256 <= qc0) || uni1;
        const int r0  = (uni && uni1) ? kc0 : 0;
        const int len = uni ? (uni1 ? MK - kc0 : kc0) : MK;
        const int CL = (len + 7) >> 3;
        const int cs = r0 + c * CL;
        int tn = min(cs + CL, r0 + len) - cs; if (tn < 0) tn = 0;

        const float4 q0 = qpart[gs + lane];
        const float4 q1 = qpart[gs + lane + 64];
        const float4 q2 = qpart[gs + lane + 128];
        const float4 q3 = qpart[gs + lane + 192];
        const float f0 = (gs + lane       >= qc0) ? 1.f : 0.f;
        const float f1 = (gs + lane + 64  >= qc0) ? 1.f : 0.f;
        const float f2 = (gs + lane + 128 >= qc0) ? 1.f : 0.f;
        const float f3 = (gs + lane + 192 >= qc0) ? 1.f : 0.f;
        const float is3 = 0.57735026918962576f;

        if (t < tn) sk[t] = kpart[cs + t];
        __syncthreads();

        const int SL = (tn + 15) >> 4;
        const int jb = w * SL, je = min(jb + SL, tn);

        // ---- pass 1: chunk-local max ----
        float m0 = -INFINITY, m1 = -INFINITY, m2 = -INFINITY, m3 = -INFINITY;
        if (uni) {
            #pragma unroll 4
            for (int j = jb; j < je; ++j) {
                float4 k4 = sk[j];
                m0 = fmaxf(m0, fmaf(q0.x, k4.y, fmaf(q0.y, k4.z, q0.z * k4.w)));
                m1 = fmaxf(m1, fmaf(q1.x, k4.y, fmaf(q1.y, k4.z, q1.z * k4.w)));
                m2 = fmaxf(m2, fmaf(q2.x, k4.y, fmaf(q2.y, k4.z, q2.z * k4.w)));
                m3 = fmaxf(m3, fmaf(q3.x, k4.y, fmaf(q3.y, k4.z, q3.z * k4.w)));
            }
        } else {
            #pragma unroll 4
            for (int j = jb; j < je; ++j) {
                float4 k4 = sk[j];
                float d0 = fmaf(q0.x, k4.y, fmaf(q0.y, k4.z, q0.z * k4.w));
                float d1 = fmaf(q1.x, k4.y, fmaf(q1.y, k4.z, q1.z * k4.w));
                float d2 = fmaf(q2.x, k4.y, fmaf(q2.y, k4.z, q2.z * k4.w));
                float d3 = fmaf(q3.x, k4.y, fmaf(q3.y, k4.z, q3.z * k4.w));
                m0 = fmaxf(m0, fmaf(fabsf(k4.x - f0), -1e10f, d0));
                m1 = fmaxf(m1, fmaf(fabsf(k4.x - f1), -1e10f, d1));
                m2 = fmaxf(m2, fmaf(fabsf(k4.x - f2), -1e10f, d2));
                m3 = fmaxf(m3, fmaf(fabsf(k4.x - f3), -1e10f, d3));
            }
        }
        red1[w * 257 + lane]       = m0;
        red1[w * 257 + lane + 64]  = m1;
        red1[w * 257 + lane + 128] = m2;
        red1[w * 257 + lane + 192] = m3;
        __syncthreads();
        {
            const int col = t >> 2, r4 = (t & 3) * 4;
            float mv = red1[r4 * 257 + col];
            mv = fmaxf(mv, red1[(r4 + 1) * 257 + col]);
            mv = fmaxf(mv, red1[(r4 + 2) * 257 + col]);
            mv = fmaxf(mv, red1[(r4 + 3) * 257 + col]);
            mv = fmaxf(mv, __shfl_xor(mv, 1));
            mv = fmaxf(mv, __shfl_xor(mv, 2));
            if ((t & 3) == 0) {
                red2[col] = mv;
                cmaxg[b * 256 + col] = mv;
            }
        }
        __syncthreads();
        const float mg0 = red2[lane],       cut0 = mg0 - 155.8845727f;
        const float mg1 = red2[lane + 64],  cut1 = mg1 - 155.8845727f;
        const float mg2 = red2[lane + 128], cut2 = mg2 - 155.8845727f;
        const float mg3 = red2[lane + 192], cut3 = mg3 - 155.8845727f;

        // ---- pass 2: exp near chunk max ----
        float l0 = 0.f, sz0 = 0.f, sy0 = 0.f, sx0 = 0.f;
        float l1 = 0.f, sz1 = 0.f, sy1 = 0.f, sx1 = 0.f;
        float l2 = 0.f, sz2 = 0.f, sy2 = 0.f, sx2 = 0.f;
        float l3 = 0.f, sz3 = 0.f, sy3 = 0.f, sx3 = 0.f;
        #pragma unroll 2
        for (int j = jb; j < je; ++j) {
            float4 k4 = sk[j];
            float d0 = fmaf(q0.x, k4.y, fmaf(q0.y, k4.z, q0.z * k4.w));
            float d1 = fmaf(q1.x, k4.y, fmaf(q1.y, k4.z, q1.z * k4.w));
            float d2 = fmaf(q2.x, k4.y, fmaf(q2.y, k4.z, q2.z * k4.w));
            float d3 = fmaf(q3.x, k4.y, fmaf(q3.y, k4.z, q3.z * k4.w));
            if (!uni) {
                d0 = fmaf(fabsf(k4.x - f0), -1e10f, d0);
                d1 = fmaf(fabsf(k4.x - f1), -1e10f, d1);
                d2 = fmaf(fabsf(k4.x - f2), -1e10f, d2);
                d3 = fmaf(fabsf(k4.x - f3), -1e10f, d3);
            }
            bool t0 = d0 >= cut0, t1 = d1 >= cut1, t2 = d2 >= cut2, t3 = d3 >= cut3;
            if (__any(t0 || t1 || t2 || t3)) {
                float e0 = t0 ? expf((d0 - mg0) * is3) : 0.f;
                float e1 = t1 ? expf((d1 - mg1) * is3) : 0.f;
                float e2 = t2 ? expf((d2 - mg2) * is3) : 0.f;
                float e3 = t3 ? expf((d3 - mg3) * is3) : 0.f;
                l0 += e0; sz0 = fmaf(e0, k4.y, sz0); sy0 = fmaf(e0, k4.z, sy0); sx0 = fmaf(e0, k4.w, sx0);
                l1 += e1; sz1 = fmaf(e1, k4.y, sz1); sy1 = fmaf(e1, k4.z, sy1); sx1 = fmaf(e1, k4.w, sx1);
                l2 += e2; sz2 = fmaf(e2, k4.y, sz2); sy2 = fmaf(e2, k4.z, sy2); sx2 = fmaf(e2, k4.w, sx2);
                l3 += e3; sz3 = fmaf(e3, k4.y, sz3); sy3 = fmaf(e3, k4.z, sy3); sx3 = fmaf(e3, k4.w, sx3);
            }
        }
        __syncthreads();                  // all sk reads done; pf clobbers
        pf[w * 257 + lane]       = make_float4(l0, sz0, sy0, sx0);
        pf[w * 257 + lane + 64]  = make_float4(l1, sz1, sy1, sx1);
        pf[w * 257 + lane + 128] = make_float4(l2, sz2, sy2, sx2);
        pf[w * 257 + lane + 192] = make_float4(l3, sz3, sy3, sx3);
        __syncthreads();
        {
            const int col = t >> 2, r4 = (t & 3) * 4;
            float4 a = pf[r4 * 257 + col];
            #pragma unroll
            for (int rr = 1; rr < 4; ++rr) {
                float4 p = pf[(r4 + rr) * 257 + col];
                a.x += p.x; a.y += p.y; a.z += p.z; a.w += p.w;
            }
            a.x += __shfl_xor(a.x, 1); a.y += __shfl_xor(a.y, 1);
            a.z += __shfl_xor(a.z, 1); a.w += __shfl_xor(a.w, 1);
            a.x += __shfl_xor(a.x, 2); a.y += __shfl_xor(a.y, 2);
            a.z += __shfl_xor(a.z, 2); a.w += __shfl_xor(a.w, 2);
            if ((t & 3) == 0) partg[b * 256 + col] = a;
        }
    }
    grid_barrier(bar, 2);

    // ========== P3: chunk merge + MLP + K64 (32 queries per block) ==========
    if (t < 32) {
        const int s = b * 32 + t;
        const int g = s >> 8, q = s & 255;
        const float is3 = 0.57735026918962576f;
        float cc[8];
        float C = -INFINITY;
        #pragma unroll
        for (int c = 0; c < 8; ++c) {
            cc[c] = cmaxg[(g * 8 + c) * 256 + q];
            C = fmaxf(C, cc[c]);
        }
        float L = 0.f, SZ = 0.f, SY = 0.f, SX = 0.f;
        if (C != -INFINITY) {
            #pragma unroll
            for (int c = 0; c < 8; ++c) {         // ascending chunk order
                float scale = expf((cc[c] - C) * is3);  // kills masked garbage
                float4 p = partg[(g * 8 + c) * 256 + q];
                L  = fmaf(p.x, scale, L);
                SZ = fmaf(p.y, scale, SZ);
                SY = fmaf(p.z, scale, SY);
                SX = fmaf(p.w, scale, SX);
            }
        }
        const float4 qq = qpart[s];
        const int qid = __float_as_int(qq.w);
        float inv = (L > 0.f) ? 1.f / L : 0.f;
        float cz = SZ * inv, cy = SY * inv, cx = SX * inv;
        float logit = b2v[0];
        #pragma unroll
        for (int k = 0; k < 32; ++k) {
            float h = b1v[k] + cz * w1[k] + cy * w1[32 + k] + cx * w1[64 + k];
            h = fmaxf(h, 0.f);
            logit += h * w2[k];
        }
        float p = 1.f / (1.f + expf(-logit));
        out[102400 + qid] = p;
        K64[qid] = ((ull)__float_as_uint(p) << 32) | (unsigned)qid;
    }
    grid_barrier(bar, 3);

    // ========== P4: rank (ballot transpose) + scatter ========================
    {
        const int ib = b * 32;
        const ull kiv = K64[ib + (lane & 31)];
        const int kilo = (int)(unsigned)kiv, kihi = (int)(unsigned)(kiv >> 32);

        const int jb = w * 512;
        ull kj[8];
        #pragma unroll
        for (int r = 0; r < 8; ++r) kj[r] = K64[jb + r * 64 + lane];

        int acc = 0;
        for (int i = 0; i < 32; ++i) {
            unsigned lo = (unsigned)__builtin_amdgcn_readlane(kilo, i);
            unsigned hi = (unsigned)__builtin_amdgcn_readlane(kihi, i);
            ull ki = ((ull)hi << 32) | lo;
            int c = 0;
            #pragma unroll
            for (int r = 0; r < 8; ++r)
                c += (int)__popcll(__ballot(kj[r] < ki));
            acc += (lane == i) ? c : 0;
        }
        if (lane < 32) scnt[w][lane] = acc;
        __syncthreads();
        if (t < 32) {
            int rank = 0;
            #pragma unroll
            for (int ww = 0; ww < 16; ++ww) rank += scnt[ww][t];
            rks[t] = rank;
        }
        __syncthreads();

        const int il = t >> 5, r = t & 31;
        const int rank = rks[il];
        if (rank >= KEEP) {
            const int p = rank - KEEP;
            const int i = ib + il;
            if (r < 20) {
                out[16384 + p * 20 + r] = voxels[i * 20 + r];
            } else if (r < 24) {
                const int* vc = (const int*)&vcoords[i];
                out[p * 4 + (r - 20)] = (float)vc[r - 20];
            } else if (r == 24) {
                out[98304 + p] = __uint_as_float((unsigned)(K64[i] >> 32));
            }
        }
    }
}

extern "C" void kernel_launch(void* const* d_in, const int* in_sizes, int n_in,
                              void* d_out, int out_size, void* d_ws, size_t ws_size,
                              hipStream_t stream) {
    const int4*   vcoords = (const int4*)d_in[0];
    const float4* kcoords = (const float4*)d_in[1];
    const float*  voxels  = (const float*)d_in[2];
    const float*  w1      = (const float*)d_in[3];
    const float*  b1      = (const float*)d_in[4];
    const float*  w2      = (const float*)d_in[5];
    const float*  b2      = (const float*)d_in[6];
    float* out = (float*)d_out;

    hipMemsetAsync(d_ws, 0, 64, stream);   // zero grid-barrier state
    fused_kernel<<<NBLK, 1024, 0, stream>>>(vcoords, kcoords, voxels,
                                            w1, b1, w2, b2, out, d_ws);
}

// Round 9
// 104.423 us; speedup vs baseline: 1.4172x; 1.4172x over previous
//
#include <hip/hip_runtime.h>
#include <math.h>

#define NQ   8192
#define MK   8192
#define KEEP 4096

// ---- ws byte offsets ----
#define OFF_CMAX   0          // 256 blk x 256 q f32 chunk max      (256 KB)
#define OFF_PART   262144     // 256 blk x 256 q float4 partials    (1 MB)
#define OFF_K64    1310720    // 8192 u64 sort keys                 (64 KB)

// out layout (floats):
//   [0,16384) coords | [16384,98304) voxels | [98304,102400) kept_imp
//   [102400,110592) importance

typedef unsigned long long ull;

// ------------------------------------------------- attention (2-pass, masked)
// block = (q-group g of 256 queries, key-chunk c of 8 x 1024 keys). 16 waves
// share the same 256 queries (4/thread); wave w scans its 64-key slice of the
// staged chunk via uniform ds_read_b128 broadcast (1 read feeds 256 dots).
// Batch mask: dm = dot - |kb - qb|*1e10 (matched -> fma(0,.,dot)==dot exactly;
// mismatched -> ~-1e10, never passes the cutoff => exact 0 contribution).
// Chunk-local softmax shift; merge kernel rescales by exp((c-C)/sqrt3) and
// annihilates all-masked-chunk garbage (scale==0).
__global__ __launch_bounds__(1024) void attn_kernel(
    const int4*   __restrict__ vcoords,
    const float4* __restrict__ kcoords,
    float* __restrict__ ws)
{
    __shared__ __align__(16) char smem[65792];
    float4* sk   = (float4*)smem;                     // [0,16384) key chunk
    float*  red1 = (float*)(smem + 16384);            // 16 x 257 f32
    float*  red2 = (float*)(smem + 16384 + 16448);    // 256 f32
    float4* pf   = (float4*)smem;                     // 16 x 257 f4 (overlay)

    float*  cmaxg = (float*)((char*)ws + OFF_CMAX);
    float4* partg = (float4*)((char*)ws + OFF_PART);

    const int b = blockIdx.x;
    const int g = b >> 3, c = b & 7;
    const int gs = g * 256, cs = c * 1024;
    const int t = threadIdx.x, w = t >> 6, lane = t & 63;

    const int4 v0 = vcoords[gs + lane];
    const int4 v1 = vcoords[gs + lane + 64];
    const int4 v2 = vcoords[gs + lane + 128];
    const int4 v3 = vcoords[gs + lane + 192];
    const float qb0 = (float)v0.x, qz0 = (float)v0.y, qy0 = (float)v0.z, qx0 = (float)v0.w;
    const float qb1 = (float)v1.x, qz1 = (float)v1.y, qy1 = (float)v1.z, qx1 = (float)v1.w;
    const float qb2 = (float)v2.x, qz2 = (float)v2.y, qy2 = (float)v2.z, qx2 = (float)v2.w;
    const float qb3 = (float)v3.x, qz3 = (float)v3.y, qy3 = (float)v3.z, qx3 = (float)v3.w;
    const float is3 = 0.57735026918962576f;

    if (t < 1024) sk[t] = kcoords[cs + t];
    __syncthreads();

    const int jb = w * 64, je = jb + 64;

    // ---- pass 1: chunk-local masked max ----
    float m0 = -INFINITY, m1 = -INFINITY, m2 = -INFINITY, m3 = -INFINITY;
    #pragma unroll 4
    for (int j = jb; j < je; ++j) {
        float4 k4 = sk[j];
        float d0 = fmaf(qz0, k4.y, fmaf(qy0, k4.z, qx0 * k4.w));
        float d1 = fmaf(qz1, k4.y, fmaf(qy1, k4.z, qx1 * k4.w));
        float d2 = fmaf(qz2, k4.y, fmaf(qy2, k4.z, qx2 * k4.w));
        float d3 = fmaf(qz3, k4.y, fmaf(qy3, k4.z, qx3 * k4.w));
        m0 = fmaxf(m0, fmaf(fabsf(k4.x - qb0), -1e10f, d0));
        m1 = fmaxf(m1, fmaf(fabsf(k4.x - qb1), -1e10f, d1));
        m2 = fmaxf(m2, fmaf(fabsf(k4.x - qb2), -1e10f, d2));
        m3 = fmaxf(m3, fmaf(fabsf(k4.x - qb3), -1e10f, d3));
    }
    red1[w * 257 + lane]       = m0;
    red1[w * 257 + lane + 64]  = m1;
    red1[w * 257 + lane + 128] = m2;
    red1[w * 257 + lane + 192] = m3;
    __syncthreads();
    {
        const int col = t >> 2, r4 = (t & 3) * 4;
        float mv = red1[r4 * 257 + col];
        mv = fmaxf(mv, red1[(r4 + 1) * 257 + col]);
        mv = fmaxf(mv, red1[(r4 + 2) * 257 + col]);
        mv = fmaxf(mv, red1[(r4 + 3) * 257 + col]);
        mv = fmaxf(mv, __shfl_xor(mv, 1));
        mv = fmaxf(mv, __shfl_xor(mv, 2));
        if ((t & 3) == 0) {
            red2[col] = mv;
            cmaxg[b * 256 + col] = mv;
        }
    }
    __syncthreads();
    const float mg0 = red2[lane],       cut0 = mg0 - 155.8845727f;
    const float mg1 = red2[lane + 64],  cut1 = mg1 - 155.8845727f;
    const float mg2 = red2[lane + 128], cut2 = mg2 - 155.8845727f;
    const float mg3 = red2[lane + 192], cut3 = mg3 - 155.8845727f;

    // ---- pass 2: exp near chunk max (90*sqrt(3) window: sub-ulp beyond) ----
    float l0 = 0.f, sz0 = 0.f, sy0 = 0.f, sx0 = 0.f;
    float l1 = 0.f, sz1 = 0.f, sy1 = 0.f, sx1 = 0.f;
    float l2 = 0.f, sz2 = 0.f, sy2 = 0.f, sx2 = 0.f;
    float l3 = 0.f, sz3 = 0.f, sy3 = 0.f, sx3 = 0.f;
    #pragma unroll 2
    for (int j = jb; j < je; ++j) {
        float4 k4 = sk[j];
        float d0 = fmaf(qz0, k4.y, fmaf(qy0, k4.z, qx0 * k4.w));
        float d1 = fmaf(qz1, k4.y, fmaf(qy1, k4.z, qx1 * k4.w));
        float d2 = fmaf(qz2, k4.y, fmaf(qy2, k4.z, qx2 * k4.w));
        float d3 = fmaf(qz3, k4.y, fmaf(qy3, k4.z, qx3 * k4.w));
        d0 = fmaf(fabsf(k4.x - qb0), -1e10f, d0);
        d1 = fmaf(fabsf(k4.x - qb1), -1e10f, d1);
        d2 = fmaf(fabsf(k4.x - qb2), -1e10f, d2);
        d3 = fmaf(fabsf(k4.x - qb3), -1e10f, d3);
        bool t0 = d0 >= cut0, t1 = d1 >= cut1, t2 = d2 >= cut2, t3 = d3 >= cut3;
        if (__any(t0 || t1 || t2 || t3)) {
            float e0 = t0 ? expf((d0 - mg0) * is3) : 0.f;
            float e1 = t1 ? expf((d1 - mg1) * is3) : 0.f;
            float e2 = t2 ? expf((d2 - mg2) * is3) : 0.f;
            float e3 = t3 ? expf((d3 - mg3) * is3) : 0.f;
            l0 += e0; sz0 = fmaf(e0, k4.y, sz0); sy0 = fmaf(e0, k4.z, sy0); sx0 = fmaf(e0, k4.w, sx0);
            l1 += e1; sz1 = fmaf(e1, k4.y, sz1); sy1 = fmaf(e1, k4.z, sy1); sx1 = fmaf(e1, k4.w, sx1);
            l2 += e2; sz2 = fmaf(e2, k4.y, sz2); sy2 = fmaf(e2, k4.z, sy2); sx2 = fmaf(e2, k4.w, sx2);
            l3 += e3; sz3 = fmaf(e3, k4.y, sz3); sy3 = fmaf(e3, k4.z, sy3); sx3 = fmaf(e3, k4.w, sx3);
        }
    }
    __syncthreads();                      // all sk reads done; pf overlays
    pf[w * 257 + lane]       = make_float4(l0, sz0, sy0, sx0);
    pf[w * 257 + lane + 64]  = make_float4(l1, sz1, sy1, sx1);
    pf[w * 257 + lane + 128] = make_float4(l2, sz2, sy2, sx2);
    pf[w * 257 + lane + 192] = make_float4(l3, sz3, sy3, sx3);
    __syncthreads();
    {
        const int col = t >> 2, r4 = (t & 3) * 4;
        float4 a = pf[r4 * 257 + col];
        #pragma unroll
        for (int rr = 1; rr < 4; ++rr) {
            float4 p = pf[(r4 + rr) * 257 + col];
            a.x += p.x; a.y += p.y; a.z += p.z; a.w += p.w;
        }
        a.x += __shfl_xor(a.x, 1); a.y += __shfl_xor(a.y, 1);
        a.z += __shfl_xor(a.z, 1); a.w += __shfl_xor(a.w, 1);
        a.x += __shfl_xor(a.x, 2); a.y += __shfl_xor(a.y, 2);
        a.z += __shfl_xor(a.z, 2); a.w += __shfl_xor(a.w, 2);
        if ((t & 3) == 0) partg[b * 256 + col] = a;
    }
}

// ------------------------------------------------- chunk merge + MLP + K64
__global__ __launch_bounds__(256) void mlp_kernel(
    const float* __restrict__ ws,
    const float* __restrict__ w1, const float* __restrict__ b1,
    const float* __restrict__ w2, const float* __restrict__ b2,
    float* __restrict__ out_imp, ull* __restrict__ K64)
{
    const int s = blockIdx.x * 256 + threadIdx.x;   // query id (natural order)
    const int g = s >> 8, q = s & 255;
    const float*  cmaxg = (const float*)((const char*)ws + OFF_CMAX);
    const float4* partg = (const float4*)((const char*)ws + OFF_PART);
    const float is3 = 0.57735026918962576f;

    float cc[8];
    float C = -INFINITY;
    #pragma unroll
    for (int c = 0; c < 8; ++c) {
        cc[c] = cmaxg[(g * 8 + c) * 256 + q];
        C = fmaxf(C, cc[c]);
    }
    float L = 0.f, SZ = 0.f, SY = 0.f, SX = 0.f;
    #pragma unroll
    for (int c = 0; c < 8; ++c) {          // ascending chunk: deterministic
        float sc = expf((cc[c] - C) * is3);     // 0 for all-masked chunks
        float4 p = partg[(g * 8 + c) * 256 + q];
        L  = fmaf(p.x, sc, L);
        SZ = fmaf(p.y, sc, SZ);
        SY = fmaf(p.z, sc, SY);
        SX = fmaf(p.w, sc, SX);
    }
    float inv = (L > 0.f) ? 1.f / L : 0.f;
    float cz = SZ * inv, cy = SY * inv, cx = SX * inv;
    float logit = b2[0];
    #pragma unroll
    for (int k = 0; k < 32; ++k) {
        float h = b1[k] + cz * w1[k] + cy * w1[32 + k] + cx * w1[64 + k];
        h = fmaxf(h, 0.f);
        logit += h * w2[k];
    }
    float p = 1.f / (1.f + expf(-logit));
    out_imp[s] = p;
    K64[s] = ((ull)__float_as_uint(p) << 32) | (unsigned)s;
}

// ------------------------------------------------- rank + scatter
// rank(i) = #{j: K_j < K_i}; distinct keys => permutation == stable argsort.
__global__ __launch_bounds__(1024) void rank_scatter_kernel(
    const ull* __restrict__ K,
    const int4* __restrict__ vcoords,
    const float* __restrict__ voxels,
    float* __restrict__ out)
{
    __shared__ int scnt[16][32];
    __shared__ int rks[32];
    const int t = threadIdx.x, w = t >> 6, lane = t & 63;
    const int ib = blockIdx.x * 32;

    const ull kiv = K[ib + (lane & 31)];
    const int kilo = (int)(unsigned)kiv, kihi = (int)(unsigned)(kiv >> 32);

    const int jb = w * 512;
    ull kj[8];
    #pragma unroll
    for (int r = 0; r < 8; ++r) kj[r] = K[jb + r * 64 + lane];

    int acc = 0;
    for (int i = 0; i < 32; ++i) {
        unsigned lo = (unsigned)__builtin_amdgcn_readlane(kilo, i);
        unsigned hi = (unsigned)__builtin_amdgcn_readlane(kihi, i);
        ull ki = ((ull)hi << 32) | lo;
        int c = 0;
        #pragma unroll
        for (int r = 0; r < 8; ++r)
            c += (int)__popcll(__ballot(kj[r] < ki));
        acc += (lane == i) ? c : 0;
    }
    if (lane < 32) scnt[w][lane] = acc;
    __syncthreads();
    if (t < 32) {
        int rank = 0;
        #pragma unroll
        for (int ww = 0; ww < 16; ++ww) rank += scnt[ww][t];
        rks[t] = rank;
    }
    __syncthreads();

    const int il = t >> 5, r = t & 31;
    const int rank = rks[il];
    if (rank >= KEEP) {
        const int p = rank - KEEP;
        const int i = ib + il;
        if (r < 20) {
            out[16384 + p * 20 + r] = voxels[i * 20 + r];
        } else if (r < 24) {
            const int* vc = (const int*)&vcoords[i];
            out[p * 4 + (r - 20)] = (float)vc[r - 20];
        } else if (r == 24) {
            out[98304 + p] = __uint_as_float((unsigned)(K[i] >> 32));
        }
    }
}

extern "C" void kernel_launch(void* const* d_in, const int* in_sizes, int n_in,
                              void* d_out, int out_size, void* d_ws, size_t ws_size,
                              hipStream_t stream) {
    const int4*   vcoords = (const int4*)d_in[0];
    const float4* kcoords = (const float4*)d_in[1];
    const float*  voxels  = (const float*)d_in[2];
    const float*  w1      = (const float*)d_in[3];
    const float*  b1      = (const float*)d_in[4];
    const float*  w2      = (const float*)d_in[5];
    const float*  b2      = (const float*)d_in[6];
    float* out = (float*)d_out;
    float* ws  = (float*)d_ws;
    ull* K64   = (ull*)((char*)d_ws + OFF_K64);

    attn_kernel<<<256, 1024, 0, stream>>>(vcoords, kcoords, ws);
    mlp_kernel<<<32, 256, 0, stream>>>(ws, w1, b1, w2, b2, out + 102400, K64);
    rank_scatter_kernel<<<256, 1024, 0, stream>>>(K64, vcoords, voxels, out);
}